// Round 1
// baseline (247.903 us; speedup 1.0000x reference)
//
#include <hip/hip_runtime.h>
#include <stdint.h>

typedef __bf16 bf16x8 __attribute__((ext_vector_type(8)));
typedef float f32x4 __attribute__((ext_vector_type(4)));

using gvoid = const __attribute__((address_space(1))) void;
using lvoid = __attribute__((address_space(3))) void;

__device__ __forceinline__ unsigned short f2bf(float f) {
    union { float f; unsigned u; } x; x.f = f;
    unsigned u = x.u;
    u += 0x7FFFu + ((u >> 16) & 1u);   // round-to-nearest-even
    return (unsigned short)(u >> 16);
}

// ---------------- A fp32 -> bf16 ----------------
__global__ void convert_bf16(const float* __restrict__ in,
                             unsigned short* __restrict__ out, int nv4) {
    int idx = blockIdx.x * blockDim.x + threadIdx.x;
    int stride = gridDim.x * blockDim.x;
    const float4* in4 = (const float4*)in;
    ushort4* out4 = (ushort4*)out;
    for (int i = idx; i < nv4; i += stride) {
        float4 v = in4[i];
        ushort4 o;
        o.x = f2bf(v.x); o.y = f2bf(v.y); o.z = f2bf(v.z); o.w = f2bf(v.w);
        out4[i] = o;
    }
}

// ---------------- Yt = (X @ W + b)^T  as bf16 [64][8192] ----------------
// cols j >= cout are zeroed (so the big GEMM can always run BN=64).
template <int CIN>
__global__ __launch_bounds__(256) void small_gemm(const float* __restrict__ X,
                                                  const float* __restrict__ W,
                                                  const float* __restrict__ b,
                                                  int cout,
                                                  unsigned short* __restrict__ Yt) {
    __shared__ float Xs[64 * (CIN + 1)];   // +1 pad: bank = (i + k) % 32, conflict-free
    __shared__ float Ws[CIN * 64];
    __shared__ float bs[64];
    const int t = threadIdx.x;
    const int i0 = blockIdx.x * 64;

    for (int e = t; e < 64 * CIN; e += 256) {
        int r = e / CIN, c = e % CIN;
        Xs[r * (CIN + 1) + c] = X[(size_t)(i0 + r) * CIN + c];
    }
    for (int e = t; e < CIN * 64; e += 256) {
        int k = e >> 6, j = e & 63;
        Ws[e] = (j < cout) ? W[k * cout + j] : 0.0f;
    }
    if (t < 64) bs[t] = (t < cout) ? b[t] : 0.0f;
    __syncthreads();

    const int i = t & 63;      // row within block (lane-varying -> coalesced writes)
    const int jg = t >> 6;     // wave-uniform j-group -> Ws reads broadcast
    float acc[16];
#pragma unroll
    for (int jj = 0; jj < 16; ++jj) acc[jj] = 0.0f;

    for (int k = 0; k < CIN; ++k) {
        float xv = Xs[i * (CIN + 1) + k];
        const float4* wr = (const float4*)&Ws[k * 64 + jg * 16];
#pragma unroll
        for (int q = 0; q < 4; ++q) {
            float4 w = wr[q];
            acc[q * 4 + 0] += xv * w.x;
            acc[q * 4 + 1] += xv * w.y;
            acc[q * 4 + 2] += xv * w.z;
            acc[q * 4 + 3] += xv * w.w;
        }
    }
#pragma unroll
    for (int jj = 0; jj < 16; ++jj) {
        int j = jg * 16 + jj;
        Yt[(size_t)j * 8192 + i0 + i] = f2bf(acc[jj] + bs[j]);
    }
}

// ---------------- big GEMM: P[ks] = A[rows, kslice] @ Y[kslice, 64] ----------------
// BM=128, BN=64, BK=64, 4 waves (2M x 2N), split-K = 4, double-buffered LDS.
// XOR swizzle (chunk c ^= row&7) applied on the *global source* of
// global_load_lds (linear LDS dest) and on the ds_read address (rule #21).
__global__ __launch_bounds__(256) void big_gemm(const unsigned short* __restrict__ Ab,
                                                const unsigned short* __restrict__ Yt,
                                                float* __restrict__ P) {
    __shared__ unsigned short As[2][128 * 64];  // 2 x 16 KB
    __shared__ unsigned short Bs[2][64 * 64];   // 2 x 8 KB
    const int t = threadIdx.x;
    const int lane = t & 63, wid = t >> 6;
    const int lane15 = lane & 15, lane4 = lane >> 4;
    const int wm = wid >> 1, wn = wid & 1;
    const int row0 = blockIdx.x * 128;
    const int kbase = blockIdx.y * 2048;

    f32x4 acc[4][2];
    const f32x4 z4 = {0.f, 0.f, 0.f, 0.f};
#pragma unroll
    for (int m = 0; m < 4; ++m)
#pragma unroll
        for (int n = 0; n < 2; ++n) acc[m][n] = z4;

    auto stage = [&](int nb, int kt) {
        // A tile: 128 rows x 64 k = 1024 16B-chunks
#pragma unroll
        for (int ii = 0; ii < 4; ++ii) {
            int p = ii * 256 + wid * 64 + lane;     // linear LDS chunk slot
            int r = p >> 3;
            int c = (p & 7) ^ (r & 7);              // inverse swizzle on source
            const unsigned short* gp = Ab + (size_t)(row0 + r) * 8192 + (kt + c * 8);
            unsigned short* lp = &As[nb][(ii * 256 + wid * 64) * 8];  // wave-uniform
            __builtin_amdgcn_global_load_lds((gvoid*)gp, (lvoid*)lp, 16, 0, 0);
        }
        // B tile (Yt rows): 64 n x 64 k = 512 chunks
#pragma unroll
        for (int ii = 0; ii < 2; ++ii) {
            int q = ii * 256 + wid * 64 + lane;
            int n = q >> 3;
            int c = (q & 7) ^ (n & 7);
            const unsigned short* gp = Yt + (size_t)n * 8192 + (kt + c * 8);
            unsigned short* lp = &Bs[nb][(ii * 256 + wid * 64) * 8];
            __builtin_amdgcn_global_load_lds((gvoid*)gp, (lvoid*)lp, 16, 0, 0);
        }
    };

    stage(0, kbase);
    __syncthreads();
    int buf = 0;
    for (int tt = 0; tt < 32; ++tt) {
        if (tt + 1 < 32) stage(buf ^ 1, kbase + (tt + 1) * 64);
#pragma unroll
        for (int ks = 0; ks < 2; ++ks) {
            bf16x8 af[4], bfr[2];
#pragma unroll
            for (int m = 0; m < 4; ++m) {
                int r = wm * 64 + m * 16 + lane15;
                int c = ks * 4 + lane4;
                af[m] = *(const bf16x8*)&As[buf][((r << 3) | (c ^ (r & 7))) << 3];
            }
#pragma unroll
            for (int n = 0; n < 2; ++n) {
                int rn = wn * 32 + n * 16 + lane15;
                int c = ks * 4 + lane4;
                bfr[n] = *(const bf16x8*)&Bs[buf][((rn << 3) | (c ^ (rn & 7))) << 3];
            }
#pragma unroll
            for (int m = 0; m < 4; ++m)
#pragma unroll
                for (int n = 0; n < 2; ++n)
                    acc[m][n] = __builtin_amdgcn_mfma_f32_16x16x32_bf16(
                        af[m], bfr[n], acc[m][n], 0, 0, 0);
        }
        __syncthreads();
        buf ^= 1;
    }

    // C/D layout: col = lane&15, row = (lane>>4)*4 + q  (guide-verified)
    float* Po = P + (size_t)blockIdx.y * (8192 * 64);
#pragma unroll
    for (int m = 0; m < 4; ++m) {
        int r = row0 + wm * 64 + m * 16 + lane4 * 4;
#pragma unroll
        for (int n = 0; n < 2; ++n) {
            int cc = wn * 32 + n * 16 + lane15;
#pragma unroll
            for (int q = 0; q < 4; ++q)
                Po[(size_t)(r + q) * 64 + cc] = acc[m][n][q];
        }
    }
}

// ---------------- reduce split-K partials + polynomial epilogue ----------------
// MODE 0: X_out = poly(z)            (layer 1)
// MODE 1: X_out = xres + poly(z)     (layer 2, residual)
// MODE 2: out[8192x40] = poly(z)     (layer 3)
template <int MODE>
__global__ void reduce_poly(const float* __restrict__ P, const float* __restrict__ cf,
                            const float* __restrict__ xres, float* __restrict__ out) {
    int t = blockIdx.x * 256 + threadIdx.x;
    const int NT = 8192 * 64;
    float z = P[t] + P[t + NT] + P[t + 2 * NT] + P[t + 3 * NT];
    float c0 = cf[0], c1 = cf[1], c2 = cf[2];
    float v = z * (c0 + z * (c1 + z * c2));
    if (MODE == 1) v += xres[t];
    if (MODE == 2) {
        int i = t >> 6, j = t & 63;
        if (j < 40) out[(size_t)i * 40 + j] = v;
    } else {
        out[t] = v;
    }
}

extern "C" void kernel_launch(void* const* d_in, const int* in_sizes, int n_in,
                              void* d_out, int out_size, void* d_ws, size_t ws_size,
                              hipStream_t stream) {
    const float* nf   = (const float*)d_in[0];
    const float* Amat = (const float*)d_in[1];
    const float* W1   = (const float*)d_in[2];
    const float* b1   = (const float*)d_in[3];
    const float* c1   = (const float*)d_in[4];
    const float* W2   = (const float*)d_in[5];
    const float* b2   = (const float*)d_in[6];
    const float* c2   = (const float*)d_in[7];
    const float* W3   = (const float*)d_in[8];
    const float* b3   = (const float*)d_in[9];
    const float* c3   = (const float*)d_in[10];
    float* out = (float*)d_out;

    char* ws = (char*)d_ws;
    unsigned short* Abf = (unsigned short*)(ws);                 // 134217728 B
    unsigned short* Yt  = (unsigned short*)(ws + 134217728);     //   1048576 B
    float* X1           = (float*)(ws + 135266304);              //   2097152 B
    float* X2           = (float*)(ws + 137363456);              //   2097152 B
    float* Pp           = (float*)(ws + 139460608);              //   8388608 B
    // total: 147849216 B

    convert_bf16<<<4096, 256, 0, stream>>>(Amat, Abf, 8192 * 8192 / 4);

    // layer 1
    small_gemm<128><<<128, 256, 0, stream>>>(nf, W1, b1, 64, Yt);
    big_gemm<<<dim3(64, 4), 256, 0, stream>>>(Abf, Yt, Pp);
    reduce_poly<0><<<2048, 256, 0, stream>>>(Pp, c1, nullptr, X1);

    // layer 2 (residual)
    small_gemm<64><<<128, 256, 0, stream>>>(X1, W2, b2, 64, Yt);
    big_gemm<<<dim3(64, 4), 256, 0, stream>>>(Abf, Yt, Pp);
    reduce_poly<1><<<2048, 256, 0, stream>>>(Pp, c2, X1, X2);

    // layer 3
    small_gemm<64><<<128, 256, 0, stream>>>(X2, W3, b3, 40, Yt);
    big_gemm<<<dim3(64, 4), 256, 0, stream>>>(Abf, Yt, Pp);
    reduce_poly<2><<<2048, 256, 0, stream>>>(Pp, c3, nullptr, out);
}

// Round 2
// 212.872 us; speedup vs baseline: 1.1646x; 1.1646x over previous
//
#include <hip/hip_runtime.h>
#include <stdint.h>

typedef __bf16 bf16x8 __attribute__((ext_vector_type(8)));
typedef float f32x4 __attribute__((ext_vector_type(4)));

using gvoid = const __attribute__((address_space(1))) void;
using lvoid = __attribute__((address_space(3))) void;

__device__ __forceinline__ unsigned short f2bf(float f) {
    union { float f; unsigned u; } x; x.f = f;
    unsigned u = x.u;
    u += 0x7FFFu + ((u >> 16) & 1u);   // round-to-nearest-even
    return (unsigned short)(u >> 16);
}
__device__ __forceinline__ unsigned pack2(float lo, float hi) {
    return ((unsigned)f2bf(hi) << 16) | (unsigned)f2bf(lo);
}

// ---------------- Yt = (X @ W + b)^T  as bf16 [64][8192], layer 1 only ----------------
template <int CIN>
__global__ __launch_bounds__(256) void small_gemm(const float* __restrict__ X,
                                                  const float* __restrict__ W,
                                                  const float* __restrict__ b,
                                                  int cout,
                                                  unsigned short* __restrict__ Yt) {
    __shared__ float Xs[64 * (CIN + 1)];
    __shared__ float Ws[CIN * 64];
    __shared__ float bs[64];
    const int t = threadIdx.x;
    const int i0 = blockIdx.x * 64;

    for (int e = t; e < 64 * CIN; e += 256) {
        int r = e / CIN, c = e % CIN;
        Xs[r * (CIN + 1) + c] = X[(size_t)(i0 + r) * CIN + c];
    }
    for (int e = t; e < CIN * 64; e += 256) {
        int k = e >> 6, j = e & 63;
        Ws[e] = (j < cout) ? W[k * cout + j] : 0.0f;
    }
    if (t < 64) bs[t] = (t < cout) ? b[t] : 0.0f;
    __syncthreads();

    const int i = t & 63;
    const int jg = t >> 6;
    float acc[16];
#pragma unroll
    for (int jj = 0; jj < 16; ++jj) acc[jj] = 0.0f;

    for (int k = 0; k < CIN; ++k) {
        float xv = Xs[i * (CIN + 1) + k];
        const float4* wr = (const float4*)&Ws[k * 64 + jg * 16];
#pragma unroll
        for (int q = 0; q < 4; ++q) {
            float4 w = wr[q];
            acc[q * 4 + 0] += xv * w.x;
            acc[q * 4 + 1] += xv * w.y;
            acc[q * 4 + 2] += xv * w.z;
            acc[q * 4 + 3] += xv * w.w;
        }
    }
#pragma unroll
    for (int jj = 0; jj < 16; ++jj) {
        int j = jg * 16 + jj;
        Yt[(size_t)j * 8192 + i0 + i] = f2bf(acc[jj] + bs[j]);
    }
}

// ---------------- big GEMM: P[ks] = A[rows, kslice] @ Y[kslice, 64] ----------------
// BM=128, BN=64, BK=64, 4 waves (2M x 2N), split-K = 8 (512 blocks -> 2 blocks/CU),
// double-buffered LDS, XOR swizzle (chunk c ^= row&7).
// CONV=1: A is read as fp32, converted in registers, ds_written (swizzled) AND
// stored to Ab (bf16) for later layers. CONV=0: A staged from Ab via
// global_load_lds with source-side inverse swizzle (linear LDS dest).
template <int CONV>
__global__ __launch_bounds__(256) void big_gemm(const float* __restrict__ Afp,
                                                unsigned short* __restrict__ Ab,
                                                const unsigned short* __restrict__ Yt,
                                                float* __restrict__ P) {
    __shared__ unsigned short As[2][128 * 64];  // 2 x 16 KB
    __shared__ unsigned short Bs[2][64 * 64];   // 2 x 8 KB
    const int t = threadIdx.x;
    const int lane = t & 63, wid = t >> 6;
    const int lane15 = lane & 15, lane4 = lane >> 4;
    const int wm = wid >> 1, wn = wid & 1;
    const int row0 = blockIdx.x * 128;
    const int kbase = blockIdx.y * 1024;   // split-K = 8

    f32x4 acc[4][2];
    const f32x4 z4 = {0.f, 0.f, 0.f, 0.f};
#pragma unroll
    for (int m = 0; m < 4; ++m)
#pragma unroll
        for (int n = 0; n < 2; ++n) acc[m][n] = z4;

    float4 ra[4][2];  // CONV reg staging: 4 chunks x 8 fp32

    auto loadA_regs = [&](int kt) {
#pragma unroll
        for (int ii = 0; ii < 4; ++ii) {
            int p = ii * 256 + t;
            int r = p >> 3, cl = p & 7;
            const float* gp = Afp + (size_t)(row0 + r) * 8192 + kt + cl * 8;
            ra[ii][0] = *(const float4*)gp;
            ra[ii][1] = *(const float4*)(gp + 4);
        }
    };
    auto writeA = [&](int nb, int kt) {
#pragma unroll
        for (int ii = 0; ii < 4; ++ii) {
            int p = ii * 256 + t;
            int r = p >> 3, cl = p & 7;
            uint4 ch;
            ch.x = pack2(ra[ii][0].x, ra[ii][0].y);
            ch.y = pack2(ra[ii][0].z, ra[ii][0].w);
            ch.z = pack2(ra[ii][1].x, ra[ii][1].y);
            ch.w = pack2(ra[ii][1].z, ra[ii][1].w);
            *(uint4*)&As[nb][((r << 3) | (cl ^ (r & 7))) << 3] = ch;           // swizzled
            *(uint4*)&Ab[(size_t)(row0 + r) * 8192 + kt + cl * 8] = ch;        // linear
        }
    };
    auto stageA = [&](int nb, int kt) {
#pragma unroll
        for (int ii = 0; ii < 4; ++ii) {
            int p = ii * 256 + wid * 64 + lane;
            int r = p >> 3;
            int c = (p & 7) ^ (r & 7);  // inverse swizzle on source, linear dest
            const unsigned short* gp = Ab + (size_t)(row0 + r) * 8192 + (kt + c * 8);
            unsigned short* lp = &As[nb][(ii * 256 + wid * 64) * 8];
            __builtin_amdgcn_global_load_lds((gvoid*)gp, (lvoid*)lp, 16, 0, 0);
        }
    };
    auto stageB = [&](int nb, int kt) {
#pragma unroll
        for (int ii = 0; ii < 2; ++ii) {
            int q = ii * 256 + wid * 64 + lane;
            int n = q >> 3;
            int c = (q & 7) ^ (n & 7);
            const unsigned short* gp = Yt + (size_t)n * 8192 + (kt + c * 8);
            unsigned short* lp = &Bs[nb][(ii * 256 + wid * 64) * 8];
            __builtin_amdgcn_global_load_lds((gvoid*)gp, (lvoid*)lp, 16, 0, 0);
        }
    };

    if (CONV) {
        loadA_regs(kbase);
        stageB(0, kbase);
        writeA(0, kbase);
    } else {
        stageA(0, kbase);
        stageB(0, kbase);
    }
    __syncthreads();

    int buf = 0;
    const int NIT = 16;  // 1024 / 64
    for (int tt = 0; tt < NIT; ++tt) {
        const bool pre = (tt + 1 < NIT);
        const int kt1 = kbase + (tt + 1) * 64;
        if (pre) {
            if (CONV) {
                loadA_regs(kt1);   // issue early — latency hides under MFMA below
                stageB(buf ^ 1, kt1);
            } else {
                stageA(buf ^ 1, kt1);
                stageB(buf ^ 1, kt1);
            }
        }
#pragma unroll
        for (int ks = 0; ks < 2; ++ks) {
            bf16x8 af[4], bfr[2];
#pragma unroll
            for (int m = 0; m < 4; ++m) {
                int r = wm * 64 + m * 16 + lane15;
                int c = ks * 4 + lane4;
                af[m] = *(const bf16x8*)&As[buf][((r << 3) | (c ^ (r & 7))) << 3];
            }
#pragma unroll
            for (int n = 0; n < 2; ++n) {
                int rn = wn * 32 + n * 16 + lane15;
                int c = ks * 4 + lane4;
                bfr[n] = *(const bf16x8*)&Bs[buf][((rn << 3) | (c ^ (rn & 7))) << 3];
            }
#pragma unroll
            for (int m = 0; m < 4; ++m)
#pragma unroll
                for (int n = 0; n < 2; ++n)
                    acc[m][n] = __builtin_amdgcn_mfma_f32_16x16x32_bf16(
                        af[m], bfr[n], acc[m][n], 0, 0, 0);
        }
        if (CONV && pre) writeA(buf ^ 1, kt1);  // write-late: cvt+ds_write+global_store
        __syncthreads();
        buf ^= 1;
    }

    // C/D layout: col = lane&15, row = (lane>>4)*4 + q
    float* Po = P + (size_t)blockIdx.y * (8192 * 64);
#pragma unroll
    for (int m = 0; m < 4; ++m) {
        int r = row0 + wm * 64 + m * 16 + lane4 * 4;
#pragma unroll
        for (int n = 0; n < 2; ++n) {
            int cc = wn * 32 + n * 16 + lane15;
#pragma unroll
            for (int q = 0; q < 4; ++q)
                Po[(size_t)(r + q) * 64 + cc] = acc[m][n][q];
        }
    }
}

// ---------------- fused: reduce split-K + poly + next layer's small GEMM ----------------
// MODE 0: X1 = poly(z); store X1; Yt = (X1 Wn + bn)^T
// MODE 1: v = X1 + poly(z) (residual, X2 never materialized); Yt = (v Wn + bn)^T
template <int MODE>
__global__ __launch_bounds__(256) void fused_reduce(const float* __restrict__ P,
                                                    const float* __restrict__ cf,
                                                    const float* __restrict__ Wn,
                                                    const float* __restrict__ bn,
                                                    int cout,
                                                    float* __restrict__ X1,
                                                    unsigned short* __restrict__ Yt) {
    __shared__ float Xs[64 * 65];
    __shared__ float Ws[64 * 64];
    __shared__ float bs[64];
    const int t = threadIdx.x;
    const int i0 = blockIdx.x * 64;
    const size_t NT = 8192 * 64;

    for (int e = t; e < 64 * 64; e += 256) {
        int k = e >> 6, j = e & 63;
        Ws[e] = (j < cout) ? Wn[k * cout + j] : 0.0f;
    }
    if (t < 64) bs[t] = (t < cout) ? bn[t] : 0.0f;
    const float c0 = cf[0], c1 = cf[1], c2 = cf[2];

    for (int s = 0; s < 16; ++s) {
        int e = s * 256 + t;
        int i = e >> 6, j = e & 63;
        size_t base = (size_t)(i0 + i) * 64 + j;
        float z = 0.f;
#pragma unroll
        for (int ks = 0; ks < 8; ++ks) z += P[ks * NT + base];
        float v = z * (c0 + z * (c1 + z * c2));
        if (MODE == 0) X1[base] = v;
        else           v += X1[base];
        Xs[i * 65 + j] = v;
    }
    __syncthreads();

    const int i = t & 63;
    const int jg = t >> 6;
    float acc[16];
#pragma unroll
    for (int jj = 0; jj < 16; ++jj) acc[jj] = 0.0f;
    for (int k = 0; k < 64; ++k) {
        float xv = Xs[i * 65 + k];
        const float4* wr = (const float4*)&Ws[k * 64 + jg * 16];
#pragma unroll
        for (int q = 0; q < 4; ++q) {
            float4 w = wr[q];
            acc[q * 4 + 0] += xv * w.x;
            acc[q * 4 + 1] += xv * w.y;
            acc[q * 4 + 2] += xv * w.z;
            acc[q * 4 + 3] += xv * w.w;
        }
    }
#pragma unroll
    for (int jj = 0; jj < 16; ++jj) {
        int j = jg * 16 + jj;
        Yt[(size_t)j * 8192 + i0 + i] = f2bf(acc[jj] + bs[j]);
    }
}

// ---------------- final: reduce + poly -> out [8192 x 40] ----------------
__global__ void reduce_out(const float* __restrict__ P, const float* __restrict__ cf,
                           float* __restrict__ out) {
    int t = blockIdx.x * 256 + threadIdx.x;
    const size_t NT = 8192 * 64;
    float z = 0.f;
#pragma unroll
    for (int ks = 0; ks < 8; ++ks) z += P[ks * NT + t];
    float c0 = cf[0], c1 = cf[1], c2 = cf[2];
    float v = z * (c0 + z * (c1 + z * c2));
    int i = t >> 6, j = t & 63;
    if (j < 40) out[(size_t)i * 40 + j] = v;
}

extern "C" void kernel_launch(void* const* d_in, const int* in_sizes, int n_in,
                              void* d_out, int out_size, void* d_ws, size_t ws_size,
                              hipStream_t stream) {
    const float* nf   = (const float*)d_in[0];
    const float* Amat = (const float*)d_in[1];
    const float* W1   = (const float*)d_in[2];
    const float* b1   = (const float*)d_in[3];
    const float* c1   = (const float*)d_in[4];
    const float* W2   = (const float*)d_in[5];
    const float* b2   = (const float*)d_in[6];
    const float* c2   = (const float*)d_in[7];
    const float* W3   = (const float*)d_in[8];
    const float* b3   = (const float*)d_in[9];
    const float* c3   = (const float*)d_in[10];
    float* out = (float*)d_out;

    char* ws = (char*)d_ws;
    unsigned short* Abf = (unsigned short*)(ws);                 // 134217728 B
    unsigned short* Yt  = (unsigned short*)(ws + 134217728);     //   1048576 B
    float* X1           = (float*)(ws + 135266304);              //   2097152 B
    float* Pp           = (float*)(ws + 137363456);              //  16777216 B
    // total: 154140672 B

    // layer 1 (fused A-conversion: writes Abf for layers 2/3)
    small_gemm<128><<<128, 256, 0, stream>>>(nf, W1, b1, 64, Yt);
    big_gemm<1><<<dim3(64, 8), 256, 0, stream>>>(Amat, Abf, Yt, Pp);
    fused_reduce<0><<<128, 256, 0, stream>>>(Pp, c1, W2, b2, 64, X1, Yt);

    // layer 2 (residual folded into fused_reduce<1>)
    big_gemm<0><<<dim3(64, 8), 256, 0, stream>>>(nullptr, Abf, Yt, Pp);
    fused_reduce<1><<<128, 256, 0, stream>>>(Pp, c2, W3, b3, 40, X1, Yt);

    // layer 3
    big_gemm<0><<<dim3(64, 8), 256, 0, stream>>>(nullptr, Abf, Yt, Pp);
    reduce_out<<<2048, 256, 0, stream>>>(Pp, c3, out);
}